// Round 4
// baseline (272.876 us; speedup 1.0000x reference)
//
#include <hip/hip_runtime.h>
#include <math.h>

#define N_NODES 10000
#define N_EDGES 160000
#define G_SEG 16
#define ZDIM 10
#define KDIM 64
#define NBESS 8
#define HIDR 16
#define RMAXF 5.0f
#define AVG_NEI_F 16.0f
#define TBINS 256
#define ZROW (TBINS+1)     // zeroed table row: padding lanes interpolate to exactly 0
#define LSTR 68            // LDS row stride (floats): 16B-aligned, banks spread

__device__ __forceinline__ float siluf(float x){ float s = 1.0f/(1.0f+expf(-x)); return x*s; }
__device__ __forceinline__ float dsiluf(float x){ float s = 1.0f/(1.0f+expf(-x)); return s*(1.0f + x*(1.0f-s)); }

__device__ __forceinline__ float waveReduce(float v){
  for (int off = 32; off > 0; off >>= 1) v += __shfl_down(v, off);
  return v;
}

// broadcast-read a lane's float via v_readlane (constant lane after unroll)
__device__ __forceinline__ float rlane(float v, int l){
  return __int_as_float(__builtin_amdgcn_readlane(__float_as_int(v), l));
}

// per-node gather. Decode hoisted: each lane decodes ITS edge once; loop
// shuffles pre-decoded (bin, frac). Padding lanes -> ZROW (zero row), no mask.
#define GATHER_NODE(NODE, PTR, PACK, IDXEXPR, LOADH, OUT) { \
  int beg_ = PTR[NODE]; int deg_ = PTR[(NODE)+1] - beg_; \
  float a0_=0.f,a1_=0.f,a2_=0.f,a3_=0.f; \
  for (int base_=0; base_<deg_; base_+=64){ \
    int m_ = min(64, deg_-base_); \
    int b_l = ZROW; float f_l = 0.f; int ix_l = 0; \
    if (lane < m_){ \
      int4 pk = PACK[beg_+base_+lane]; \
      float tp_ = __int_as_float(pk.x) * (TBINS/RMAXF); \
      b_l = (int)tp_; f_l = tp_ - (float)b_l; ix_l = IDXEXPR; \
    } \
    int mr_ = (m_ + 7) & ~7; \
    for (int i_=0; i_<mr_; i_+=8){ \
      int b0_=__shfl(b_l,i_),   b1_=__shfl(b_l,i_+1), b2_=__shfl(b_l,i_+2), b3_=__shfl(b_l,i_+3); \
      int b4_=__shfl(b_l,i_+4), b5_=__shfl(b_l,i_+5), b6_=__shfl(b_l,i_+6), b7_=__shfl(b_l,i_+7); \
      float f0_=__shfl(f_l,i_),   f1_=__shfl(f_l,i_+1), f2_=__shfl(f_l,i_+2), f3_=__shfl(f_l,i_+3); \
      float f4_=__shfl(f_l,i_+4), f5_=__shfl(f_l,i_+5), f6_=__shfl(f_l,i_+6), f7_=__shfl(f_l,i_+7); \
      int s0_=__shfl(ix_l,i_),   s1_=__shfl(ix_l,i_+1), s2_=__shfl(ix_l,i_+2), s3_=__shfl(ix_l,i_+3); \
      int s4_=__shfl(ix_l,i_+4), s5_=__shfl(ix_l,i_+5), s6_=__shfl(ix_l,i_+6), s7_=__shfl(ix_l,i_+7); \
      float2 F0_=Ft2[b0_*KDIM+lane]; float h0_=LOADH(s0_); \
      float2 F1_=Ft2[b1_*KDIM+lane]; float h1_=LOADH(s1_); \
      float2 F2_=Ft2[b2_*KDIM+lane]; float h2_=LOADH(s2_); \
      float2 F3_=Ft2[b3_*KDIM+lane]; float h3_=LOADH(s3_); \
      float2 F4_=Ft2[b4_*KDIM+lane]; float h4_=LOADH(s4_); \
      float2 F5_=Ft2[b5_*KDIM+lane]; float h5_=LOADH(s5_); \
      float2 F6_=Ft2[b6_*KDIM+lane]; float h6_=LOADH(s6_); \
      float2 F7_=Ft2[b7_*KDIM+lane]; float h7_=LOADH(s7_); \
      a0_ += (F0_.x + f0_*(F0_.y-F0_.x))*h0_; a1_ += (F1_.x + f1_*(F1_.y-F1_.x))*h1_; \
      a2_ += (F2_.x + f2_*(F2_.y-F2_.x))*h2_; a3_ += (F3_.x + f3_*(F3_.y-F3_.x))*h3_; \
      a0_ += (F4_.x + f4_*(F4_.y-F4_.x))*h4_; a1_ += (F5_.x + f5_*(F5_.y-F5_.x))*h5_; \
      a2_ += (F6_.x + f6_*(F6_.y-F6_.x))*h6_; a3_ += (F7_.x + f7_*(F7_.y-F7_.x))*h7_; \
    } } \
  OUT = ((a0_+a1_)+(a2_+a3_)); }

// stage 2 KxK matrices (row-major [row][k]) into LDS with row stride LSTR.
#define STAGE2(W0P, W1P) { \
  for (int idx_ = tid; idx_ < KDIM*KDIM; idx_ += 512){ \
    int r_ = idx_ >> 6, c_ = idx_ & 63; \
    smW[0][r_*LSTR + c_] = (W0P)[idx_]; \
    smW[1][r_*LSTR + c_] = (W1P)[idx_]; \
  } \
  __syncthreads(); }

// barrier-free wave-local matvec: out[lane] = sum_k X[k] * smW[M][lane][k]
#define MVLDS(XV, M, OUT) { \
  const float* Lr_ = &smW[M][lane*LSTR]; \
  float m0_=0.f,m1_=0.f,m2_=0.f,m3_=0.f; \
  _Pragma("unroll") \
  for (int kq_=0; kq_<KDIM/4; kq_++){ \
    float4 mm_ = *(const float4*)&Lr_[4*kq_]; \
    m0_ += rlane(XV,4*kq_+0)*mm_.x; \
    m1_ += rlane(XV,4*kq_+1)*mm_.y; \
    m2_ += rlane(XV,4*kq_+2)*mm_.z; \
    m3_ += rlane(XV,4*kq_+3)*mm_.w; \
  } \
  OUT = (m0_+m1_)+(m2_+m3_); }

// per-wave K=64 matvec from register V via readlane + GLOBAL weight rows
#define MVTROW(XV, MT, ROW, OUT) { \
  const float4* Mr_ = (const float4*)((MT) + (ROW)*KDIM); \
  float m0a_=0.f,m1a_=0.f,m2a_=0.f,m3a_=0.f; \
  _Pragma("unroll") \
  for (int kq_=0; kq_<KDIM/4; kq_++){ \
    float4 mm_ = Mr_[kq_]; \
    m0a_ += rlane(XV,4*kq_+0)*mm_.x; \
    m1a_ += rlane(XV,4*kq_+1)*mm_.y; \
    m2a_ += rlane(XV,4*kq_+2)*mm_.z; \
    m3a_ += rlane(XV,4*kq_+3)*mm_.w; \
  } \
  OUT = (m0a_+m1a_)+(m2a_+m3a_); }
#define MVT(XV, MT, OUT) MVTROW(XV, MT, lane, OUT)

#define LOADH_PLAIN(S) rows[(S)*KDIM + lane]
#define LOADH_G2(S)    gAr2c[(S)*KDIM + lane].x
#define LOADH_M0(S)    smM[(S)*KDIM + lane]

#define NTABW 514            // 2 layers x 257 bins, one wave each
#define SETUP_BASE 302
#define NSETUP (SETUP_BASE + (NTABW+3)/4)   // 302 + 129 = 431 blocks

// ---------------- merged setup + wave-local table build ----------------
// block map:
//   0..4    M0 / Msc0                (1280)
//   5..36   WoT0 / WoT1 transposes   (8192)
//   37..52  Cmu0 = Wmix0*Wup1 (R+T)  (4096, write 2)
//   53..212 WCzT = (Wmix0*Wsc1[z])^T (40960)
//   213..216 P1T + P1H               (1024, write 2)
//   217..256 QtabT                   (10240)
//   257..296 z_buf / e_node / cnt=0  (10000)
//   297..300 Wr1T                    (1024)
//   301     pv0                      (64)
//   302..   radial table build
__global__ __launch_bounds__(256) void k_setup(
    const float* We, const float* Wup, const float* Wsc,
    const float* Wout, const float* Wmix,
    const float* Wr1, const float* w_read0,
    const float* attrs, const float* aE,
    const float* R1g, const float* R2g, const float* R3g, const float* R4g,
    float* M0, float* Msc0,
    float* WoT0, float* WoT1,
    float* Cmu0R, float* Cmu0T, float* WCzT,
    float* P1T, float* P1H, float* QtabT, float* Wr1T, float* pv0,
    float2* Ft2_0, float2* Ft2_1, float* dF4f,
    int* z_buf, float* e_node, int* cnt_r, int* cnt_s){
  int blk = blockIdx.x, tid = threadIdx.x;
  const float* Wmix1 = Wmix + KDIM*KDIM;
  const float* Wup1  = Wup + KDIM*KDIM;
  const float* Wsc1  = Wsc + ZDIM*KDIM*KDIM;
  if (blk < 5){
    int idx = blk*256 + tid;
    if (idx < 1280){
      int which = idx >= 640;
      int t = which ? idx - 640 : idx;
      int z = t >> 6, j = t & 63;
      float acc = 0.f;
      if (!which){
        #pragma unroll 8
        for (int k = 0; k < KDIM; k++) acc += We[z*KDIM + k] * Wup[k*KDIM + j];
        M0[z*KDIM + j] = acc;
      } else {
        #pragma unroll 8
        for (int k = 0; k < KDIM; k++) acc += We[z*KDIM + k] * Wsc[(z*KDIM + k)*KDIM + j];
        Msc0[z*KDIM + j] = acc;
      }
    }
  } else if (blk < 37){
    int t = (blk-5)*256 + tid;   // 0..8191
    int arr = t >> 12;
    int rem = t & 4095;
    int j = rem >> 6, k = rem & 63;
    if (arr == 0) WoT0[rem] = Wout[k*KDIM + j];
    else          WoT1[rem] = Wout[3*KDIM*KDIM + k*KDIM + j];
  } else if (blk < 53){
    int t = (blk-37)*256 + tid;  // 0..4095: Cmu0[r][c] = sum_k Wmix0[r][k]*Wup1[k][c]
    int r = t >> 6, c = t & 63;
    float acc = 0.f;
    #pragma unroll 8
    for (int k = 0; k < KDIM; k++) acc += Wmix[r*KDIM + k] * Wup1[k*KDIM + c];
    Cmu0R[r*KDIM + c] = acc;
    Cmu0T[c*KDIM + r] = acc;
  } else if (blk < 213){
    int t = (blk-53)*256 + tid;  // 0..40959: WCzT[z][j][m] = sum_k Wmix0[m][k]*Wsc1[z][k][j]
    int z = t >> 12; int rem = t & 4095;
    int j = rem >> 6, m = rem & 63;
    float acc = 0.f;
    #pragma unroll 8
    for (int k = 0; k < KDIM; k++) acc += Wmix[m*KDIM + k] * Wsc1[(z*KDIM + k)*KDIM + j];
    WCzT[(z*KDIM + j)*KDIM + m] = acc;
  } else if (blk < 217){
    int t = (blk-213)*256 + tid;  // 0..1023: P1[k][h] = sum_j Wr1[j][h]*Wmix1[k][j]
    int h = t >> 6, k = t & 63;
    float acc = 0.f;
    #pragma unroll 8
    for (int j = 0; j < KDIM; j++) acc += Wr1[j*HIDR + h] * Wmix1[k*KDIM + j];
    P1T[k*HIDR + h] = acc;
    P1H[h*KDIM + k] = acc;
  } else if (blk < 257){
    int t = (blk-217)*256 + tid;  // 0..10239: QtabT[z][k][h] = sum_j Wr1[j][h]*Wsc1[z][k][j]
    int z = t >> 10;
    int rem = t & 1023;
    int h = rem >> 6, k = rem & 63;
    float acc = 0.f;
    #pragma unroll 8
    for (int j = 0; j < KDIM; j++) acc += Wr1[j*HIDR + h] * Wsc1[(z*KDIM + k)*KDIM + j];
    QtabT[(z*KDIM + k)*HIDR + h] = acc;
  } else if (blk < 297){
    int n = (blk-257)*256 + tid;
    if (n < N_NODES){
      int z = 0;
      for (int i = 1; i < ZDIM; i++) if (attrs[n*ZDIM+i] > 0.5f) z = i;
      z_buf[n] = z;
      e_node[n] = aE[z];
      cnt_r[n] = 0; cnt_s[n] = 0;
    }
  } else if (blk < 301){
    int t = (blk-297)*256 + tid; // 0..1023
    int h = t >> 6, j = t & 63;
    Wr1T[h*KDIM + j] = Wr1[j*HIDR + h];    // [h][j]
  } else if (blk < 302){
    if (tid < KDIM){
      float acc = 0.f;
      #pragma unroll 8
      for (int j = 0; j < KDIM; j++) acc += Wmix[tid*KDIM + j] * w_read0[j];
      pv0[tid] = acc;
    }
  } else {
    // wave-local radial-MLP table build: one (layer,bin) per wave, no barriers
    int w = tid >> 6, j = tid & 63;
    int wave_id = (blk - SETUP_BASE)*4 + w;
    if (wave_id >= NTABW) return;
    int i = wave_id / (TBINS+1);
    int t = wave_id % (TBINS+1);
    float efv = 0.f, defv = 0.f;
    {
      double r = (double)t * (double)RMAXF / (double)TBINS;
      double wfr = (double)(j+1) * M_PI / (double)RMAXF;
      double c = sqrt(2.0 / (double)RMAXF);
      double bess, dbess;
      if (r < 1e-12){ bess = c*wfr; dbess = 0.0; }
      else {
        double sw = sin(wfr*r), cw = cos(wfr*r);
        bess = c*sw/r;
        dbess = c*(wfr*cw*r - sw)/(r*r);
      }
      double xx = r / (double)RMAXF;
      double f = 0.0, df = 0.0;
      if (xx < 1.0){
        double x2 = xx*xx, x4 = x2*x2, x5 = x4*xx, x6 = x5*xx, x7 = x6*xx;
        f = 1.0 - 21.0*x5 + 35.0*x6 - 15.0*x7;
        df = (-105.0*x4 + 210.0*x5 - 105.0*x6) / (double)RMAXF;
      }
      efv  = (float)(bess*f);
      defv = (float)(dbess*f + bess*df);
    }
    const float* R1 = R1g + i*NBESS*KDIM;
    const float* R2 = R2g + i*KDIM*KDIM;
    const float* R3 = R3g + i*KDIM*KDIM;
    const float* R4 = R4g + i*KDIM*KDIM;
    float z = 0.f, dz = 0.f;
    #pragma unroll
    for (int b = 0; b < NBESS; b++){
      float ef = __shfl(efv, b), def = __shfl(defv, b);
      float wv = R1[b*KDIM+j];
      z += ef*wv; dz += def*wv;
    }
    float v = siluf(z), dv = dsiluf(z)*dz;
    z = 0.f; dz = 0.f;
    for (int k = 0; k < KDIM; k++){
      float xv = __shfl(v, k), dxv = __shfl(dv, k);
      float wv = R2[k*KDIM+j];
      z += xv*wv; dz += dxv*wv;
    }
    float v2 = siluf(z), dv2 = dsiluf(z)*dz;
    z = 0.f; dz = 0.f;
    for (int k = 0; k < KDIM; k++){
      float xv = __shfl(v2, k), dxv = __shfl(dv2, k);
      float wv = R3[k*KDIM+j];
      z += xv*wv; dz += dxv*wv;
    }
    float v3 = siluf(z), dv3 = dsiluf(z)*dz;
    z = 0.f; dz = 0.f;
    for (int k = 0; k < KDIM; k++){
      float xv = __shfl(v3, k), dxv = __shfl(dv3, k);
      float wv = R4[k*KDIM+j];
      z += xv*wv; dz += dxv*wv;
    }
    float2* Ft = i ? Ft2_1 : Ft2_0;
    Ft[t*KDIM+j].x = z;  if (t > 0) Ft[(t-1)*KDIM+j].y = z;
    dF4f[(t*KDIM+j)*4 + 2*i] = dz;
    if (t > 0) dF4f[((t-1)*KDIM+j)*4 + 2*i + 1] = dz;
    if (t == 0) Ft[ZROW*KDIM + j] = make_float2(0.f, 0.f);   // zero row for padding lanes
  }
}

#define EB_MAIN (N_EDGES/256)     // 625
#define EB_TAIL 46                // derived tables needing Msc0/QtabT

__global__ __launch_bounds__(256) void k_edge_setup(const float* pos, const float* shifts, const int* ei,
                                                    const int* z_buf,
                                                    const float* Wmix, const float* Wup, const float* Wsc,
                                                    const float* Msc0, const float* QtabT, const float* w_read0,
                                                    float* Q2tab, float* biash, float* biass, float* c0z,
                                                    float4* evec, int4* emeta,
                                                    int* cnt_r, int* cnt_s){
  int tid = threadIdx.x;
  if (blockIdx.x >= EB_MAIN){
    int tb = blockIdx.x - EB_MAIN;
    const float* Wup1 = Wup + KDIM*KDIM;
    const float* Wsc1 = Wsc + ZDIM*KDIM*KDIM;
    if (tb < 40){
      // Q2tab[z][k][h] = sum_j Wmix0[k][j] * QtabT[z][j][h]
      int idx = tb*256 + tid;   // 0..10239
      int z = idx >> 10; int rem = idx & 1023;
      int k = rem >> 4, h = rem & 15;
      float acc = 0.f;
      #pragma unroll 8
      for (int j = 0; j < KDIM; j++)
        acc += Wmix[k*KDIM + j] * QtabT[(z*KDIM + j)*HIDR + h];
      Q2tab[(z*KDIM + k)*HIDR + h] = acc;
    } else if (tb < 45){
      int idx = (tb-40)*256 + tid;   // 0..1279
      if (idx < 1280){
        int which = idx >= 640;
        int t = which ? idx - 640 : idx;
        int z = t >> 6, j = t & 63;
        float acc = 0.f;
        if (!which){
          #pragma unroll 8
          for (int k = 0; k < KDIM; k++) acc += Msc0[z*KDIM + k] * Wup1[k*KDIM + j];
          biash[z*KDIM + j] = acc;
        } else {
          #pragma unroll 8
          for (int k = 0; k < KDIM; k++) acc += Msc0[z*KDIM + k] * Wsc1[(z*KDIM + k)*KDIM + j];
          biass[z*KDIM + j] = acc;
        }
      }
    } else {
      if (tid < ZDIM){
        float acc = 0.f;
        #pragma unroll 8
        for (int j = 0; j < KDIM; j++) acc += Msc0[tid*KDIM + j] * w_read0[j];
        c0z[tid] = acc;
      }
    }
    return;
  }
  int e = blockIdx.x*256 + tid;
  int s = ei[e], rcv = ei[N_EDGES + e];
  float dx = pos[rcv*3+0] - pos[s*3+0] + shifts[e*3+0];
  float dy = pos[rcv*3+1] - pos[s*3+1] + shifts[e*3+1];
  float dz = pos[rcv*3+2] - pos[s*3+2] + shifts[e*3+2];
  float r = sqrtf(dx*dx + dy*dy + dz*dz + 1e-9f);
  evec[e] = make_float4(dx, dy, dz, r);
  emeta[e] = make_int4(__float_as_int(r), s, rcv, z_buf[s]);
  if (r < RMAXF){
    atomicAdd(&cnt_s[s], 1);
    atomicAdd(&cnt_r[rcv], 1);
  }
}

// shuffle-based scan: 2 barriers total
__global__ __launch_bounds__(1024) void k_scan(const int* cnt_r, int* ptr_r, int* cur_r,
                                               const int* cnt_s, int* ptr_s, int* cur_s){
  __shared__ int wtot[16];
  __shared__ int woff[16];
  int tid = threadIdx.x;
  int w = tid >> 6, lane = tid & 63;
  const int* cnt = blockIdx.x ? cnt_s : cnt_r;
  int* ptr = blockIdx.x ? ptr_s : ptr_r;
  int* cur = blockIdx.x ? cur_s : cur_r;
  const int per = 10;
  int start = tid*per;
  int csum = 0;
  int cl[per];
  #pragma unroll
  for (int t = 0; t < per; t++){
    int i = start + t;
    int c = (i < N_NODES) ? cnt[i] : 0;
    cl[t] = c; csum += c;
  }
  int v = csum;
  #pragma unroll
  for (int off = 1; off < 64; off <<= 1){
    int u = __shfl_up(v, off);
    if (lane >= off) v += u;
  }
  if (lane == 63) wtot[w] = v;
  __syncthreads();
  if (w == 0 && lane < 16){
    int t = wtot[lane];
    int sv = t;
    #pragma unroll
    for (int off = 1; off < 16; off <<= 1){
      int u = __shfl_up(sv, off);
      if (lane >= off) sv += u;
    }
    woff[lane] = sv - t;
    if (lane == 15) ptr[N_NODES] = sv;
  }
  __syncthreads();
  int run = woff[w] + v - csum;
  #pragma unroll
  for (int t = 0; t < per; t++){
    int i = start + t;
    if (i < N_NODES){ ptr[i] = run; cur[i] = run; run += cl[t]; }
  }
}

__global__ __launch_bounds__(256) void k_fill(const int4* emeta, int* cur_r, int* cur_s,
                                              int4* pr_pack, int4* ps_pack){
  int e = blockIdx.x*256 + threadIdx.x;
  int4 m = emeta[e];            // {r_bits, snd, rcv, ez}
  float r = __int_as_float(m.x);
  if (r >= RMAXF) return;
  int p = atomicAdd(&cur_s[m.y], 1);
  ps_pack[p] = make_int4(m.x, m.z, e, 0);          // {r, rcv, eid}
  int p2 = atomicAdd(&cur_r[m.z], 1);
  pr_pack[p2] = make_int4(m.x, m.y, m.w, e);       // {r, snd, ez, eid}
}

// ---------------- layer-0: gather + folded barrier-free epilogue ----------------
__global__ __launch_bounds__(512) void k_layer0_fwd(
    const int* z_buf, const int* ptr_r, const int4* pr_pack,
    const float2* Ft2, const float* M0g,
    const float* WoT0, const float* Cmu0T, const float* WCzT,
    const float* theta0, const float* biash, const float* biass,
    const float* pv0, const float* c0z,
    float* A0_out, float* h1, float* sc1, float* e_node){
  __shared__ __align__(16) float smW[2][KDIM*LSTR];
  __shared__ float smM[ZDIM*KDIM];
  int tid = threadIdx.x;
  int w = tid >> 6, lane = tid & 63;
  for (int idx_ = tid; idx_ < KDIM*KDIM; idx_ += 512){
    int r_ = idx_ >> 6, c_ = idx_ & 63;
    smW[0][r_*LSTR + c_] = WoT0[idx_];
    smW[1][r_*LSTR + c_] = Cmu0T[idx_];
  }
  for (int idx_ = tid; idx_ < ZDIM*KDIM; idx_ += 512) smM[idx_] = M0g[idx_];
  __syncthreads();
  int node = blockIdx.x*8 + w;
  int z = z_buf[node];
  float acc;
  GATHER_NODE(node, ptr_r, pr_pack, pk.z, LOADH_M0, acc)
  acc *= (1.0f/AVG_NEI_F);
  float a0;
  MVLDS(acc, 0, a0)
  A0_out[node*KDIM+lane] = a0;
  float t0 = theta0[(0*ZDIM+z)*KDIM+lane];
  float t1 = theta0[(1*ZDIM+z)*KDIM+lane];
  float t2 = theta0[(2*ZDIM+z)*KDIM+lane];
  float v = (t0 + t1*a0 + t2*a0*a0)*a0;
  // energy readout: f.w_read0 = v.pv0 + c0[z]
  float p = waveReduce(v * pv0[lane]);
  if (lane == 0) e_node[node] += p + c0z[z];
  // h1 = (Wmix0*Wup1)^T v + biash[z]
  float h;
  MVLDS(v, 1, h)
  h1[node*KDIM+lane] = h + biash[z*KDIM+lane];
  // sc1 = (Wmix0*Wsc1[z])^T v + biass[z]
  float s;
  MVT(v, WCzT + z*KDIM*KDIM, s)
  sc1[node*KDIM+lane] = s + biass[z*KDIM+lane];
}

// ---------------- layer-1 fwd + node-local bwd (f never materialized) ----------------
__global__ __launch_bounds__(512) void k_layer1_fwd_bwd(
    const int* z_buf, const int* ptr_r, const int4* pr_pack,
    const float2* Ft2, const float* h1rows,
    const float* WoT1, const float* Wout1raw,
    const float* theta1,
    const float* sc1, const float* P1H, const float* Wr1T, const float* Wr2,
    const float* P1T, const float* Q2tab, const float* pv0,
    float2* gAr2, float* gF1, float* e_node){
  __shared__ __align__(16) float smW[2][KDIM*LSTR];
  int tid = threadIdx.x;
  int w = tid >> 6, lane = tid & 63;
  STAGE2(WoT1, Wout1raw)
  int node = blockIdx.x*8 + w;
  int z = z_buf[node];
  const float* rows = h1rows;
  float acc;
  GATHER_NODE(node, ptr_r, pr_pack, pk.y, LOADH_PLAIN, acc)
  acc *= (1.0f/AVG_NEI_F);
  float a0;
  MVLDS(acc, 0, a0)
  float t0 = theta1[(0*ZDIM+z)*KDIM+lane];
  float t1 = theta1[(1*ZDIM+z)*KDIM+lane];
  float t2 = theta1[(2*ZDIM+z)*KDIM+lane];
  float v = (t0 + t1*a0 + t2*a0*a0)*a0;
  float scv = sc1[node*KDIM+lane];
  int hh = lane & 15;
  // tpart = (Wmix1^T Wr1)[.,hh].v + Wr1[.,hh].sc1
  float tpa, tpb;
  MVTROW(v,   P1H,  hh, tpa)
  MVTROW(scv, Wr1T, hh, tpb)
  float tpart = tpa + tpb;
  float wr2 = Wr2[hh];
  float ne = waveReduce(siluf(tpart)*wr2);
  if (lane == 0) e_node[node] += 0.25f*ne;   // per-node, single owner wave: no atomic
  float coeff = dsiluf(tpart)*wr2;
  float gP, gs2;
  { const float4* Pp_ = (const float4*)(P1T + lane*HIDR);
    const float4* Qp_ = (const float4*)(Q2tab + (z*KDIM + lane)*HIDR);
    float pa0_=0.f,pa1_=0.f,pa2_=0.f,pa3_=0.f, qa0_=0.f,qa1_=0.f,qa2_=0.f,qa3_=0.f;
    #pragma unroll
    for (int hq_=0; hq_<HIDR/4; hq_++){
      float4 pm_ = Pp_[hq_]; float4 qm_ = Qp_[hq_];
      float c0_=rlane(coeff,4*hq_+0), c1_=rlane(coeff,4*hq_+1);
      float c2_=rlane(coeff,4*hq_+2), c3_=rlane(coeff,4*hq_+3);
      pa0_ += c0_*pm_.x; pa1_ += c1_*pm_.y; pa2_ += c2_*pm_.z; pa3_ += c3_*pm_.w;
      qa0_ += c0_*qm_.x; qa1_ += c1_*qm_.y; qa2_ += c2_*qm_.z; qa3_ += c3_*qm_.w;
    }
    gP = (pa0_+pa1_)+(pa2_+pa3_); gs2 = (qa0_+qa1_)+(qa2_+qa3_);
  }
  // gF1' = Wmix0^T(dE/dfeats1 non-gather part) = pv0 + gs2
  gF1[node*KDIM+lane] = pv0[lane] + gs2;
  float u = t0 + 2.f*t1*a0 + 3.f*t2*a0*a0;
  float vl = gP*u;
  float gAr;
  MVLDS(vl, 1, gAr)
  gAr2[node*KDIM+lane].x = gAr * (1.0f/AVG_NEI_F);
}

#define NBWD_NODE (N_NODES/8)           // 1250
#define NBWD_EN   ((N_NODES+511)/512)   // 20 extra blocks: fused energy reduce

// ---------------- bwd: sender-gather gH + layer-0 node bwd (+fused energy) ----------------
__global__ __launch_bounds__(512) void k_bwd_gH0(
    const int* z_buf, const int* ptr_s, const int4* ps_pack,
    const float2* Ft2, const float2* gAr2c,
    const float* Cmu0R, const float* Wout0raw,
    const float* gF1,
    const float* A00, const float* theta0,
    const float* e_node, const int* batch, float* out_e,
    float2* gAr2){
  int tid = threadIdx.x;
  if (blockIdx.x >= NBWD_NODE){
    // fused k_energy: LDS pre-reduced segment sum
    __shared__ float part[G_SEG];
    if (tid < G_SEG) part[tid] = 0.f;
    __syncthreads();
    int n = (blockIdx.x - NBWD_NODE)*512 + tid;
    if (n < N_NODES) atomicAdd(&part[batch[n]], e_node[n]);
    __syncthreads();
    if (tid < G_SEG) atomicAdd(&out_e[tid], part[tid]);
    return;
  }
  __shared__ __align__(16) float smW[2][KDIM*LSTR];
  int w = tid >> 6, lane = tid & 63;
  STAGE2(Cmu0R, Wout0raw)
  int node = blockIdx.x*8 + w;
  float ga;
  GATHER_NODE(node, ptr_s, ps_pack, pk.y, LOADH_G2, ga)
  // gP = gF1'(node) + Cmu0.ga   (Cmu0 = Wmix0*Wup1, row-major staged)
  float gfm;
  MVLDS(ga, 0, gfm)
  float gP = gF1[node*KDIM+lane] + gfm;
  int z = z_buf[node];
  float a = A00[node*KDIM+lane];
  float t0 = theta0[(0*ZDIM+z)*KDIM+lane];
  float t1 = theta0[(1*ZDIM+z)*KDIM+lane];
  float t2 = theta0[(2*ZDIM+z)*KDIM+lane];
  float u = t0 + 2.f*t1*a + 3.f*t2*a*a;
  float vl = gP*u;
  float gAr;
  MVLDS(vl, 1, gAr)
  gAr2[node*KDIM+lane].y = gAr * (1.0f/AVG_NEI_F);
}

// per-edge gr/r -> evec[e].w  (4 edges/wave, 16 lanes x 4 k each, float4 loads)
__global__ __launch_bounds__(256) void k_gr(const int4* emeta, const float4* dF4,
                                            const float2* gAr2, const float* h1, const float* M0,
                                            float4* evec){
  int tid = threadIdx.x;
  int e = blockIdx.x*16 + (tid >> 4);
  int li = tid & 15;
  int4 m = emeta[e];              // {r, snd, rcv, ez}
  float r = __int_as_float(m.x);
  if (r >= RMAXF) return;
  float tp = r * (TBINS / RMAXF);
  int b = (int)tp; if (b > TBINS-1) b = TBINS-1;
  float fr = tp - (float)b;
  int k0 = li*4;
  const float4* dp = dF4 + b*KDIM + k0;
  float4 d0 = dp[0], d1 = dp[1], d2 = dp[2], d3 = dp[3];
  const float4* gp = (const float4*)(gAr2 + m.z*KDIM + k0);
  float4 g01 = gp[0], g23 = gp[1];          // {g0.x,g0.y,g1.x,g1.y},{g2.x,g2.y,g3.x,g3.y}
  float4 hv = *(const float4*)(h1 + m.y*KDIM + k0);
  float4 mv = *(const float4*)(M0 + m.w*KDIM + k0);
  float v;
  v  = g01.x*hv.x*(d0.z + fr*(d0.w-d0.z)) + g01.y*mv.x*(d0.x + fr*(d0.y-d0.x));
  v += g01.z*hv.y*(d1.z + fr*(d1.w-d1.z)) + g01.w*mv.y*(d1.x + fr*(d1.y-d1.x));
  v += g23.x*hv.z*(d2.z + fr*(d2.w-d2.z)) + g23.y*mv.z*(d2.x + fr*(d2.y-d2.x));
  v += g23.z*hv.w*(d3.z + fr*(d3.w-d3.z)) + g23.w*mv.w*(d3.x + fr*(d3.y-d3.x));
  #pragma unroll
  for (int off = 8; off > 0; off >>= 1) v += __shfl_xor(v, off);
  if (li == 0) evec[e].w = v / r;
}

// force gather: 16 lanes/node, both CSR lists, no atomics
__global__ __launch_bounds__(256) void k_force(const int* ptr_r, const int4* pr_pack,
                                               const int* ptr_s, const int4* ps_pack,
                                               const float4* evec,
                                               float* out_f){
  int tid = threadIdx.x;
  int node = blockIdx.x*16 + (tid >> 4);
  int li = tid & 15;
  float fx=0.f, fy=0.f, fz=0.f;
  int beg = ptr_r[node], end = ptr_r[node+1];
  for (int idx = beg + li; idx < end; idx += 16){
    int e = pr_pack[idx].w;
    float4 ev = evec[e];
    fx -= ev.w*ev.x; fy -= ev.w*ev.y; fz -= ev.w*ev.z;
  }
  beg = ptr_s[node]; end = ptr_s[node+1];
  for (int idx = beg + li; idx < end; idx += 16){
    int e = ps_pack[idx].z;
    float4 ev = evec[e];
    fx += ev.w*ev.x; fy += ev.w*ev.y; fz += ev.w*ev.z;
  }
  #pragma unroll
  for (int off = 8; off > 0; off >>= 1){
    fx += __shfl_xor(fx, off);
    fy += __shfl_xor(fy, off);
    fz += __shfl_xor(fz, off);
  }
  if (li == 0){
    out_f[node*3+0] = fx; out_f[node*3+1] = fy; out_f[node*3+2] = fz;
  }
}

extern "C" void kernel_launch(void* const* d_in, const int* in_sizes, int n_in,
                              void* d_out, int out_size, void* d_ws, size_t ws_size,
                              hipStream_t stream){
  const float* pos    = (const float*)d_in[0];
  const float* attrs  = (const float*)d_in[1];
  const float* shifts = (const float*)d_in[2];
  const float* aE     = (const float*)d_in[3];
  const float* We     = (const float*)d_in[4];
  const float* Wup    = (const float*)d_in[5];
  const float* R1     = (const float*)d_in[6];
  const float* R2     = (const float*)d_in[7];
  const float* R3     = (const float*)d_in[8];
  const float* R4     = (const float*)d_in[9];
  const float* Wout   = (const float*)d_in[10];
  const float* Wsc    = (const float*)d_in[11];
  const float* theta  = (const float*)d_in[12];
  const float* Wmix   = (const float*)d_in[13];
  const float* w_read0= (const float*)d_in[14];
  const float* Wr1    = (const float*)d_in[15];
  const float* Wr2    = (const float*)d_in[16];
  const int*   ei     = (const int*)d_in[17];
  const int*   batch  = (const int*)d_in[18];

  char* base = (char*)d_ws;
  size_t off = 0;
  auto alloc = [&](size_t bytes)->void*{
    void* p = base + off;
    off = (off + bytes + 255) & ~(size_t)255;
    return p;
  };
  float4* evec   = (float4*)alloc(N_EDGES*sizeof(float4));
  int4*   emeta  = (int4*)alloc(N_EDGES*sizeof(int4));
  int4*   pr_pack= (int4*)alloc(N_EDGES*sizeof(int4));
  int4*   ps_pack= (int4*)alloc(N_EDGES*sizeof(int4));
  float*  e_node = (float*)alloc(N_NODES*sizeof(float));
  float*  h1     = (float*)alloc(N_NODES*KDIM*sizeof(float));
  float*  sc1    = (float*)alloc(N_NODES*KDIM*sizeof(float));
  float*  A00    = (float*)alloc(N_NODES*KDIM*sizeof(float));
  float*  gF1    = (float*)alloc(N_NODES*KDIM*sizeof(float));
  float2* gAr2   = (float2*)alloc(N_NODES*KDIM*sizeof(float2));
  float2* Ft2_0  = (float2*)alloc((TBINS+2)*KDIM*sizeof(float2));
  float2* Ft2_1  = (float2*)alloc((TBINS+2)*KDIM*sizeof(float2));
  float4* dF4    = (float4*)alloc((TBINS+1)*KDIM*sizeof(float4));
  float*  M0     = (float*)alloc(ZDIM*KDIM*sizeof(float));
  float*  Msc0   = (float*)alloc(ZDIM*KDIM*sizeof(float));
  float*  WoT0   = (float*)alloc(KDIM*KDIM*sizeof(float));
  float*  WoT1   = (float*)alloc(KDIM*KDIM*sizeof(float));
  float*  Cmu0R  = (float*)alloc(KDIM*KDIM*sizeof(float));
  float*  Cmu0T  = (float*)alloc(KDIM*KDIM*sizeof(float));
  float*  WCzT   = (float*)alloc(ZDIM*KDIM*KDIM*sizeof(float));
  float*  P1T    = (float*)alloc(KDIM*HIDR*sizeof(float));
  float*  P1H    = (float*)alloc(HIDR*KDIM*sizeof(float));
  float*  QtabT  = (float*)alloc(ZDIM*KDIM*HIDR*sizeof(float));
  float*  Q2tab  = (float*)alloc(ZDIM*KDIM*HIDR*sizeof(float));
  float*  Wr1T   = (float*)alloc(HIDR*KDIM*sizeof(float));
  float*  biash  = (float*)alloc(ZDIM*KDIM*sizeof(float));
  float*  biass  = (float*)alloc(ZDIM*KDIM*sizeof(float));
  float*  pv0    = (float*)alloc(KDIM*sizeof(float));
  float*  c0z    = (float*)alloc(16*sizeof(float));
  int* z_buf = (int*)alloc(N_NODES*sizeof(int));
  int* cnt_r = (int*)alloc(N_NODES*sizeof(int));
  int* cnt_s = (int*)alloc(N_NODES*sizeof(int));
  int* ptr_r = (int*)alloc((N_NODES+1)*sizeof(int));
  int* ptr_s = (int*)alloc((N_NODES+1)*sizeof(int));
  int* cur_r = (int*)alloc(N_NODES*sizeof(int));
  int* cur_s = (int*)alloc(N_NODES*sizeof(int));

  float* out_e = (float*)d_out;
  float* out_f = out_e + G_SEG;

  hipMemsetAsync(d_out, 0, (size_t)out_size*sizeof(float), stream);

  const int NB8 = N_NODES/8;

  const float* Wout1 = Wout + 3*KDIM*KDIM;
  const float* theta1 = theta + 3*ZDIM*KDIM;

  k_setup<<<NSETUP,256,0,stream>>>(We, Wup, Wsc, Wout, Wmix, Wr1, w_read0, attrs, aE,
                                   R1, R2, R3, R4,
                                   M0, Msc0, WoT0, WoT1,
                                   Cmu0R, Cmu0T, WCzT,
                                   P1T, P1H, QtabT, Wr1T, pv0,
                                   Ft2_0, Ft2_1, (float*)dF4,
                                   z_buf, e_node, cnt_r, cnt_s);
  k_edge_setup<<<EB_MAIN+EB_TAIL,256,0,stream>>>(pos, shifts, ei, z_buf,
                                   Wmix, Wup, Wsc, Msc0, QtabT, w_read0,
                                   Q2tab, biash, biass, c0z,
                                   evec, emeta, cnt_r, cnt_s);
  k_scan<<<2,1024,0,stream>>>(cnt_r, ptr_r, cur_r, cnt_s, ptr_s, cur_s);
  k_fill<<<EB_MAIN,256,0,stream>>>(emeta, cur_r, cur_s, pr_pack, ps_pack);

  // ---- forward ----
  k_layer0_fwd<<<NB8,512,0,stream>>>(z_buf, ptr_r, pr_pack, Ft2_0, M0,
      WoT0, Cmu0T, WCzT, theta, biash, biass, pv0, c0z,
      A00, h1, sc1, e_node);
  k_layer1_fwd_bwd<<<NB8,512,0,stream>>>(z_buf, ptr_r, pr_pack, Ft2_1, h1,
      WoT1, Wout1, theta1, sc1, P1H, Wr1T, Wr2,
      P1T, Q2tab, pv0,
      gAr2, gF1, e_node);

  // ---- backward (+fused energy blocks) ----
  k_bwd_gH0<<<NBWD_NODE + NBWD_EN,512,0,stream>>>(z_buf, ptr_s, ps_pack, Ft2_1, gAr2,
      Cmu0R, Wout, gF1, A00, theta,
      e_node, batch, out_e, gAr2);
  k_gr<<<N_EDGES/16,256,0,stream>>>(emeta, dF4, gAr2, h1, M0, evec);
  k_force<<<N_NODES/16,256,0,stream>>>(ptr_r, pr_pack, ptr_s, ps_pack, evec, out_f);
}

// Round 5
// 234.279 us; speedup vs baseline: 1.1648x; 1.1648x over previous
//
#include <hip/hip_runtime.h>
#include <math.h>

#define N_NODES 10000
#define N_EDGES 160000
#define G_SEG 16
#define ZDIM 10
#define KDIM 64
#define NBESS 8
#define HIDR 16
#define RMAXF 5.0f
#define AVG_NEI_F 16.0f
#define TBINS 256
#define ZROW (TBINS+1)     // zeroed table row: padding lanes interpolate to exactly 0
#define LSTR 68            // LDS row stride (floats): 16B-aligned, banks spread

__device__ __forceinline__ float siluf(float x){ float s = 1.0f/(1.0f+expf(-x)); return x*s; }
__device__ __forceinline__ float dsiluf(float x){ float s = 1.0f/(1.0f+expf(-x)); return s*(1.0f + x*(1.0f-s)); }

__device__ __forceinline__ float waveReduce(float v){
  for (int off = 32; off > 0; off >>= 1) v += __shfl_down(v, off);
  return v;
}

// broadcast-read a lane's float via v_readlane (constant lane after unroll)
__device__ __forceinline__ float rlane(float v, int l){
  return __int_as_float(__builtin_amdgcn_readlane(__float_as_int(v), l));
}

// per-node gather. Decode hoisted: each lane decodes ITS edge once; loop
// shuffles pre-decoded (bin, frac). Padding lanes -> ZROW (zero row), no mask.
#define GATHER_NODE(NODE, PTR, PACK, IDXEXPR, LOADH, OUT) { \
  int beg_ = PTR[NODE]; int deg_ = PTR[(NODE)+1] - beg_; \
  float a0_=0.f,a1_=0.f,a2_=0.f,a3_=0.f; \
  for (int base_=0; base_<deg_; base_+=64){ \
    int m_ = min(64, deg_-base_); \
    int b_l = ZROW; float f_l = 0.f; int ix_l = 0; \
    if (lane < m_){ \
      int4 pk = PACK[beg_+base_+lane]; \
      float tp_ = __int_as_float(pk.x) * (TBINS/RMAXF); \
      b_l = (int)tp_; f_l = tp_ - (float)b_l; ix_l = IDXEXPR; \
    } \
    int mr_ = (m_ + 7) & ~7; \
    for (int i_=0; i_<mr_; i_+=8){ \
      int b0_=__shfl(b_l,i_),   b1_=__shfl(b_l,i_+1), b2_=__shfl(b_l,i_+2), b3_=__shfl(b_l,i_+3); \
      int b4_=__shfl(b_l,i_+4), b5_=__shfl(b_l,i_+5), b6_=__shfl(b_l,i_+6), b7_=__shfl(b_l,i_+7); \
      float f0_=__shfl(f_l,i_),   f1_=__shfl(f_l,i_+1), f2_=__shfl(f_l,i_+2), f3_=__shfl(f_l,i_+3); \
      float f4_=__shfl(f_l,i_+4), f5_=__shfl(f_l,i_+5), f6_=__shfl(f_l,i_+6), f7_=__shfl(f_l,i_+7); \
      int s0_=__shfl(ix_l,i_),   s1_=__shfl(ix_l,i_+1), s2_=__shfl(ix_l,i_+2), s3_=__shfl(ix_l,i_+3); \
      int s4_=__shfl(ix_l,i_+4), s5_=__shfl(ix_l,i_+5), s6_=__shfl(ix_l,i_+6), s7_=__shfl(ix_l,i_+7); \
      float2 F0_=Ft2[b0_*KDIM+lane]; float h0_=LOADH(s0_); \
      float2 F1_=Ft2[b1_*KDIM+lane]; float h1_=LOADH(s1_); \
      float2 F2_=Ft2[b2_*KDIM+lane]; float h2_=LOADH(s2_); \
      float2 F3_=Ft2[b3_*KDIM+lane]; float h3_=LOADH(s3_); \
      float2 F4_=Ft2[b4_*KDIM+lane]; float h4_=LOADH(s4_); \
      float2 F5_=Ft2[b5_*KDIM+lane]; float h5_=LOADH(s5_); \
      float2 F6_=Ft2[b6_*KDIM+lane]; float h6_=LOADH(s6_); \
      float2 F7_=Ft2[b7_*KDIM+lane]; float h7_=LOADH(s7_); \
      a0_ += (F0_.x + f0_*(F0_.y-F0_.x))*h0_; a1_ += (F1_.x + f1_*(F1_.y-F1_.x))*h1_; \
      a2_ += (F2_.x + f2_*(F2_.y-F2_.x))*h2_; a3_ += (F3_.x + f3_*(F3_.y-F3_.x))*h3_; \
      a0_ += (F4_.x + f4_*(F4_.y-F4_.x))*h4_; a1_ += (F5_.x + f5_*(F5_.y-F5_.x))*h5_; \
      a2_ += (F6_.x + f6_*(F6_.y-F6_.x))*h6_; a3_ += (F7_.x + f7_*(F7_.y-F7_.x))*h7_; \
    } } \
  OUT = ((a0_+a1_)+(a2_+a3_)); }

// stage 2 KxK matrices (row-major [row][k]) into LDS with row stride LSTR.
#define STAGE2(W0P, W1P) { \
  for (int idx_ = tid; idx_ < KDIM*KDIM; idx_ += 512){ \
    int r_ = idx_ >> 6, c_ = idx_ & 63; \
    smW[0][r_*LSTR + c_] = (W0P)[idx_]; \
    smW[1][r_*LSTR + c_] = (W1P)[idx_]; \
  } \
  __syncthreads(); }

// barrier-free wave-local matvec: out[lane] = sum_k X[k] * smW[M][lane][k]
#define MVLDS(XV, M, OUT) { \
  const float* Lr_ = &smW[M][lane*LSTR]; \
  float m0_=0.f,m1_=0.f,m2_=0.f,m3_=0.f; \
  _Pragma("unroll") \
  for (int kq_=0; kq_<KDIM/4; kq_++){ \
    float4 mm_ = *(const float4*)&Lr_[4*kq_]; \
    m0_ += rlane(XV,4*kq_+0)*mm_.x; \
    m1_ += rlane(XV,4*kq_+1)*mm_.y; \
    m2_ += rlane(XV,4*kq_+2)*mm_.z; \
    m3_ += rlane(XV,4*kq_+3)*mm_.w; \
  } \
  OUT = (m0_+m1_)+(m2_+m3_); }

// COALESCED global matvec: out[lane] = sum_m X[m] * W[m*KDIM + lane]
// (each load: 64 lanes read 256 consecutive bytes -> 4 txns, vs 64 for row-per-lane)
#define MVCOL(XV, WP, OUT) { \
  const float* Wc_ = (WP) + lane; \
  float c0_=0.f,c1_=0.f,c2_=0.f,c3_=0.f; \
  _Pragma("unroll") \
  for (int m_=0; m_<KDIM; m_+=4){ \
    c0_ += rlane(XV,m_+0)*Wc_[(m_+0)*KDIM]; \
    c1_ += rlane(XV,m_+1)*Wc_[(m_+1)*KDIM]; \
    c2_ += rlane(XV,m_+2)*Wc_[(m_+2)*KDIM]; \
    c3_ += rlane(XV,m_+3)*Wc_[(m_+3)*KDIM]; \
  } \
  OUT = (c0_+c1_)+(c2_+c3_); }

#define LOADH_PLAIN(S) rows[(S)*KDIM + lane]
#define LOADH_G2(S)    gAr2c[(S)*KDIM + lane].x
#define LOADH_M0(S)    smM[(S)*KDIM + lane]

#define NTABW 514            // 2 layers x 257 bins, one wave each
#define SETUP_BASE 302
#define NSETUP (SETUP_BASE + (NTABW+3)/4)   // 302 + 129 = 431 blocks

// ---------------- merged setup + wave-local table build ----------------
__global__ __launch_bounds__(256) void k_setup(
    const float* We, const float* Wup, const float* Wsc,
    const float* Wout, const float* Wmix,
    const float* Wr1, const float* w_read0,
    const float* attrs, const float* aE,
    const float* R1g, const float* R2g, const float* R3g, const float* R4g,
    float* M0, float* Msc0,
    float* WoT0, float* WoT1,
    float* Cmu0R, float* Cmu0T, float* WCz,
    float* P1T, float* P1H, float* QtabT, float* Wr1T, float* pv0,
    float2* Ft2_0, float2* Ft2_1, float* dF4f,
    int* z_buf, float* e_node, int* cnt_r, int* cnt_s){
  int blk = blockIdx.x, tid = threadIdx.x;
  const float* Wmix1 = Wmix + KDIM*KDIM;
  const float* Wup1  = Wup + KDIM*KDIM;
  const float* Wsc1  = Wsc + ZDIM*KDIM*KDIM;
  if (blk < 5){
    int idx = blk*256 + tid;
    if (idx < 1280){
      int which = idx >= 640;
      int t = which ? idx - 640 : idx;
      int z = t >> 6, j = t & 63;
      float acc = 0.f;
      if (!which){
        #pragma unroll 8
        for (int k = 0; k < KDIM; k++) acc += We[z*KDIM + k] * Wup[k*KDIM + j];
        M0[z*KDIM + j] = acc;
      } else {
        #pragma unroll 8
        for (int k = 0; k < KDIM; k++) acc += We[z*KDIM + k] * Wsc[(z*KDIM + k)*KDIM + j];
        Msc0[z*KDIM + j] = acc;
      }
    }
  } else if (blk < 37){
    int t = (blk-5)*256 + tid;   // 0..8191
    int arr = t >> 12;
    int rem = t & 4095;
    int j = rem >> 6, k = rem & 63;
    if (arr == 0) WoT0[rem] = Wout[k*KDIM + j];
    else          WoT1[rem] = Wout[3*KDIM*KDIM + k*KDIM + j];
  } else if (blk < 53){
    int t = (blk-37)*256 + tid;  // 0..4095: Cmu0[r][c] = sum_k Wmix0[r][k]*Wup1[k][c]
    int r = t >> 6, c = t & 63;
    float acc = 0.f;
    #pragma unroll 8
    for (int k = 0; k < KDIM; k++) acc += Wmix[r*KDIM + k] * Wup1[k*KDIM + c];
    Cmu0R[r*KDIM + c] = acc;
    Cmu0T[c*KDIM + r] = acc;
  } else if (blk < 213){
    int t = (blk-53)*256 + tid;  // 0..40959: WCz[z][m][j] = sum_k Wmix0[m][k]*Wsc1[z][k][j]
    int z = t >> 12; int rem = t & 4095;
    int j = rem >> 6, m = rem & 63;
    float acc = 0.f;
    #pragma unroll 8
    for (int k = 0; k < KDIM; k++) acc += Wmix[m*KDIM + k] * Wsc1[(z*KDIM + k)*KDIM + j];
    WCz[(z*KDIM + m)*KDIM + j] = acc;   // [z][m][j]: coalesced column access
  } else if (blk < 217){
    int t = (blk-213)*256 + tid;  // 0..1023: P1[k][h] = sum_j Wr1[j][h]*Wmix1[k][j]
    int h = t >> 6, k = t & 63;
    float acc = 0.f;
    #pragma unroll 8
    for (int j = 0; j < KDIM; j++) acc += Wr1[j*HIDR + h] * Wmix1[k*KDIM + j];
    P1T[k*HIDR + h] = acc;
    P1H[h*KDIM + k] = acc;
  } else if (blk < 257){
    int t = (blk-217)*256 + tid;  // 0..10239: QtabT[z][k][h] = sum_j Wr1[j][h]*Wsc1[z][k][j]
    int z = t >> 10;
    int rem = t & 1023;
    int h = rem >> 6, k = rem & 63;
    float acc = 0.f;
    #pragma unroll 8
    for (int j = 0; j < KDIM; j++) acc += Wr1[j*HIDR + h] * Wsc1[(z*KDIM + k)*KDIM + j];
    QtabT[(z*KDIM + k)*HIDR + h] = acc;
  } else if (blk < 297){
    int n = (blk-257)*256 + tid;
    if (n < N_NODES){
      int z = 0;
      for (int i = 1; i < ZDIM; i++) if (attrs[n*ZDIM+i] > 0.5f) z = i;
      z_buf[n] = z;
      e_node[n] = aE[z];
      cnt_r[n] = 0; cnt_s[n] = 0;
    }
  } else if (blk < 301){
    int t = (blk-297)*256 + tid; // 0..1023
    int h = t >> 6, j = t & 63;
    Wr1T[h*KDIM + j] = Wr1[j*HIDR + h];    // [h][j] (kept; unused by hot path now)
  } else if (blk < 302){
    if (tid < KDIM){
      float acc = 0.f;
      #pragma unroll 8
      for (int j = 0; j < KDIM; j++) acc += Wmix[tid*KDIM + j] * w_read0[j];
      pv0[tid] = acc;
    }
  } else {
    // wave-local radial-MLP table build: one (layer,bin) per wave, no barriers
    int w = tid >> 6, j = tid & 63;
    int wave_id = (blk - SETUP_BASE)*4 + w;
    if (wave_id >= NTABW) return;
    int i = wave_id / (TBINS+1);
    int t = wave_id % (TBINS+1);
    float efv = 0.f, defv = 0.f;
    {
      double r = (double)t * (double)RMAXF / (double)TBINS;
      double wfr = (double)(j+1) * M_PI / (double)RMAXF;
      double c = sqrt(2.0 / (double)RMAXF);
      double bess, dbess;
      if (r < 1e-12){ bess = c*wfr; dbess = 0.0; }
      else {
        double sw = sin(wfr*r), cw = cos(wfr*r);
        bess = c*sw/r;
        dbess = c*(wfr*cw*r - sw)/(r*r);
      }
      double xx = r / (double)RMAXF;
      double f = 0.0, df = 0.0;
      if (xx < 1.0){
        double x2 = xx*xx, x4 = x2*x2, x5 = x4*xx, x6 = x5*xx, x7 = x6*xx;
        f = 1.0 - 21.0*x5 + 35.0*x6 - 15.0*x7;
        df = (-105.0*x4 + 210.0*x5 - 105.0*x6) / (double)RMAXF;
      }
      efv  = (float)(bess*f);
      defv = (float)(dbess*f + bess*df);
    }
    const float* R1 = R1g + i*NBESS*KDIM;
    const float* R2 = R2g + i*KDIM*KDIM;
    const float* R3 = R3g + i*KDIM*KDIM;
    const float* R4 = R4g + i*KDIM*KDIM;
    float z = 0.f, dz = 0.f;
    #pragma unroll
    for (int b = 0; b < NBESS; b++){
      float ef = __shfl(efv, b), def = __shfl(defv, b);
      float wv = R1[b*KDIM+j];
      z += ef*wv; dz += def*wv;
    }
    float v = siluf(z), dv = dsiluf(z)*dz;
    z = 0.f; dz = 0.f;
    for (int k = 0; k < KDIM; k++){
      float xv = __shfl(v, k), dxv = __shfl(dv, k);
      float wv = R2[k*KDIM+j];
      z += xv*wv; dz += dxv*wv;
    }
    float v2 = siluf(z), dv2 = dsiluf(z)*dz;
    z = 0.f; dz = 0.f;
    for (int k = 0; k < KDIM; k++){
      float xv = __shfl(v2, k), dxv = __shfl(dv2, k);
      float wv = R3[k*KDIM+j];
      z += xv*wv; dz += dxv*wv;
    }
    float v3 = siluf(z), dv3 = dsiluf(z)*dz;
    z = 0.f; dz = 0.f;
    for (int k = 0; k < KDIM; k++){
      float xv = __shfl(v3, k), dxv = __shfl(dv3, k);
      float wv = R4[k*KDIM+j];
      z += xv*wv; dz += dxv*wv;
    }
    float2* Ft = i ? Ft2_1 : Ft2_0;
    Ft[t*KDIM+j].x = z;  if (t > 0) Ft[(t-1)*KDIM+j].y = z;
    dF4f[(t*KDIM+j)*4 + 2*i] = dz;
    if (t > 0) dF4f[((t-1)*KDIM+j)*4 + 2*i + 1] = dz;
    if (t == 0) Ft[ZROW*KDIM + j] = make_float2(0.f, 0.f);   // zero row for padding lanes
  }
}

#define EB_MAIN (N_EDGES/256)     // 625
#define EB_TAIL 46                // derived tables needing Msc0/QtabT

__global__ __launch_bounds__(256) void k_edge_setup(const float* pos, const float* shifts, const int* ei,
                                                    const int* z_buf,
                                                    const float* Wmix, const float* Wup, const float* Wsc,
                                                    const float* Msc0, const float* QtabT, const float* w_read0,
                                                    float* Q2H, float* biash, float* biass, float* c0z,
                                                    float4* evec, int4* emeta,
                                                    int* cnt_r, int* cnt_s){
  int tid = threadIdx.x;
  if (blockIdx.x >= EB_MAIN){
    int tb = blockIdx.x - EB_MAIN;
    const float* Wup1 = Wup + KDIM*KDIM;
    const float* Wsc1 = Wsc + ZDIM*KDIM*KDIM;
    if (tb < 40){
      // Q2H[z][h][k] = sum_j Wmix0[k][j] * QtabT[z][j][h]  (coalesced-in-k layout)
      int idx = tb*256 + tid;   // 0..10239
      int z = idx >> 10; int rem = idx & 1023;
      int k = rem >> 4, h = rem & 15;
      float acc = 0.f;
      #pragma unroll 8
      for (int j = 0; j < KDIM; j++)
        acc += Wmix[k*KDIM + j] * QtabT[(z*KDIM + j)*HIDR + h];
      Q2H[(z*HIDR + h)*KDIM + k] = acc;
    } else if (tb < 45){
      int idx = (tb-40)*256 + tid;   // 0..1279
      if (idx < 1280){
        int which = idx >= 640;
        int t = which ? idx - 640 : idx;
        int z = t >> 6, j = t & 63;
        float acc = 0.f;
        if (!which){
          #pragma unroll 8
          for (int k = 0; k < KDIM; k++) acc += Msc0[z*KDIM + k] * Wup1[k*KDIM + j];
          biash[z*KDIM + j] = acc;
        } else {
          #pragma unroll 8
          for (int k = 0; k < KDIM; k++) acc += Msc0[z*KDIM + k] * Wsc1[(z*KDIM + k)*KDIM + j];
          biass[z*KDIM + j] = acc;
        }
      }
    } else {
      if (tid < ZDIM){
        float acc = 0.f;
        #pragma unroll 8
        for (int j = 0; j < KDIM; j++) acc += Msc0[tid*KDIM + j] * w_read0[j];
        c0z[tid] = acc;
      }
    }
    return;
  }
  int e = blockIdx.x*256 + tid;
  int s = ei[e], rcv = ei[N_EDGES + e];
  float dx = pos[rcv*3+0] - pos[s*3+0] + shifts[e*3+0];
  float dy = pos[rcv*3+1] - pos[s*3+1] + shifts[e*3+1];
  float dz = pos[rcv*3+2] - pos[s*3+2] + shifts[e*3+2];
  float r = sqrtf(dx*dx + dy*dy + dz*dz + 1e-9f);
  evec[e] = make_float4(dx, dy, dz, r);
  emeta[e] = make_int4(__float_as_int(r), s, rcv, z_buf[s]);
  if (r < RMAXF){
    atomicAdd(&cnt_s[s], 1);
    atomicAdd(&cnt_r[rcv], 1);
  }
}

// shuffle-based scan: 2 barriers total
__global__ __launch_bounds__(1024) void k_scan(const int* cnt_r, int* ptr_r, int* cur_r,
                                               const int* cnt_s, int* ptr_s, int* cur_s){
  __shared__ int wtot[16];
  __shared__ int woff[16];
  int tid = threadIdx.x;
  int w = tid >> 6, lane = tid & 63;
  const int* cnt = blockIdx.x ? cnt_s : cnt_r;
  int* ptr = blockIdx.x ? ptr_s : ptr_r;
  int* cur = blockIdx.x ? cur_s : cur_r;
  const int per = 10;
  int start = tid*per;
  int csum = 0;
  int cl[per];
  #pragma unroll
  for (int t = 0; t < per; t++){
    int i = start + t;
    int c = (i < N_NODES) ? cnt[i] : 0;
    cl[t] = c; csum += c;
  }
  int v = csum;
  #pragma unroll
  for (int off = 1; off < 64; off <<= 1){
    int u = __shfl_up(v, off);
    if (lane >= off) v += u;
  }
  if (lane == 63) wtot[w] = v;
  __syncthreads();
  if (w == 0 && lane < 16){
    int t = wtot[lane];
    int sv = t;
    #pragma unroll
    for (int off = 1; off < 16; off <<= 1){
      int u = __shfl_up(sv, off);
      if (lane >= off) sv += u;
    }
    woff[lane] = sv - t;
    if (lane == 15) ptr[N_NODES] = sv;
  }
  __syncthreads();
  int run = woff[w] + v - csum;
  #pragma unroll
  for (int t = 0; t < per; t++){
    int i = start + t;
    if (i < N_NODES){ ptr[i] = run; cur[i] = run; run += cl[t]; }
  }
}

__global__ __launch_bounds__(256) void k_fill(const int4* emeta, int* cur_r, int* cur_s,
                                              int4* pr_pack, int4* ps_pack){
  int e = blockIdx.x*256 + threadIdx.x;
  int4 m = emeta[e];            // {r_bits, snd, rcv, ez}
  float r = __int_as_float(m.x);
  if (r >= RMAXF) return;
  int p = atomicAdd(&cur_s[m.y], 1);
  ps_pack[p] = make_int4(m.x, m.z, e, 0);          // {r, rcv, eid}
  int p2 = atomicAdd(&cur_r[m.z], 1);
  pr_pack[p2] = make_int4(m.x, m.y, m.w, e);       // {r, snd, ez, eid}
}

// ---------------- layer-0: gather + folded coalesced epilogue ----------------
__global__ __launch_bounds__(512) void k_layer0_fwd(
    const int* z_buf, const int* ptr_r, const int4* pr_pack,
    const float2* Ft2, const float* M0g,
    const float* WoT0, const float* Cmu0T, const float* WCz,
    const float* theta0, const float* biash, const float* biass,
    const float* pv0, const float* c0z,
    float* A0_out, float* h1, float* sc1, float* e_node){
  __shared__ __align__(16) float smW[2][KDIM*LSTR];
  __shared__ float smM[ZDIM*KDIM];
  int tid = threadIdx.x;
  int w = tid >> 6, lane = tid & 63;
  for (int idx_ = tid; idx_ < KDIM*KDIM; idx_ += 512){
    int r_ = idx_ >> 6, c_ = idx_ & 63;
    smW[0][r_*LSTR + c_] = WoT0[idx_];
    smW[1][r_*LSTR + c_] = Cmu0T[idx_];
  }
  for (int idx_ = tid; idx_ < ZDIM*KDIM; idx_ += 512) smM[idx_] = M0g[idx_];
  __syncthreads();
  int node = blockIdx.x*8 + w;
  int z = z_buf[node];
  float acc;
  GATHER_NODE(node, ptr_r, pr_pack, pk.z, LOADH_M0, acc)
  acc *= (1.0f/AVG_NEI_F);
  float a0;
  MVLDS(acc, 0, a0)
  A0_out[node*KDIM+lane] = a0;
  float t0 = theta0[(0*ZDIM+z)*KDIM+lane];
  float t1 = theta0[(1*ZDIM+z)*KDIM+lane];
  float t2 = theta0[(2*ZDIM+z)*KDIM+lane];
  float v = (t0 + t1*a0 + t2*a0*a0)*a0;
  // energy readout: f.w_read0 = v.pv0 + c0[z]
  float p = waveReduce(v * pv0[lane]);
  if (lane == 0) e_node[node] += p + c0z[z];
  // h1 = (Wmix0*Wup1)^T v + biash[z]
  float h;
  MVLDS(v, 1, h)
  h1[node*KDIM+lane] = h + biash[z*KDIM+lane];
  // sc1 = sum_m v[m] * WCz[z][m][lane] + biass[z]   (coalesced column access)
  float s;
  MVCOL(v, WCz + z*KDIM*KDIM, s)
  sc1[node*KDIM+lane] = s + biass[z*KDIM+lane];
}

// ---------------- layer-1 fwd + node-local bwd (all-coalesced epilogue) ----------------
__global__ __launch_bounds__(512) void k_layer1_fwd_bwd(
    const int* z_buf, const int* ptr_r, const int4* pr_pack,
    const float2* Ft2, const float* h1rows,
    const float* WoT1, const float* Wout1raw,
    const float* theta1,
    const float* sc1, const float* P1T, const float* Wr1, const float* Wr2,
    const float* P1H, const float* Q2H, const float* pv0,
    float2* gAr2, float* gF1, float* e_node){
  __shared__ __align__(16) float smW[2][KDIM*LSTR];
  int tid = threadIdx.x;
  int w = tid >> 6, lane = tid & 63;
  STAGE2(WoT1, Wout1raw)
  int node = blockIdx.x*8 + w;
  int z = z_buf[node];
  const float* rows = h1rows;
  float acc;
  GATHER_NODE(node, ptr_r, pr_pack, pk.y, LOADH_PLAIN, acc)
  acc *= (1.0f/AVG_NEI_F);
  float a0;
  MVLDS(acc, 0, a0)
  float t0 = theta1[(0*ZDIM+z)*KDIM+lane];
  float t1 = theta1[(1*ZDIM+z)*KDIM+lane];
  float t2 = theta1[(2*ZDIM+z)*KDIM+lane];
  float v = (t0 + t1*a0 + t2*a0*a0)*a0;
  float scv = sc1[node*KDIM+lane];
  int hh = lane & 15;
  // tpart[hh] = sum_k v[k]*P1T[k][hh] + sum_k sc1[k]*Wr1[k][hh]
  // broadcast-coalesced: lanes with same hh read identical 16-float rows
  float tpa, tpb;
  { const float* Pt_ = P1T + hh;
    const float* Wt_ = Wr1 + hh;
    float pa_=0.f,pb_=0.f,pc_=0.f,pd_=0.f;
    #pragma unroll
    for (int k = 0; k < KDIM; k += 2){
      pa_ += rlane(v,  k  )*Pt_[ k   *HIDR];
      pb_ += rlane(v,  k+1)*Pt_[(k+1)*HIDR];
      pc_ += rlane(scv,k  )*Wt_[ k   *HIDR];
      pd_ += rlane(scv,k+1)*Wt_[(k+1)*HIDR];
    }
    tpa = pa_+pb_; tpb = pc_+pd_;
  }
  float tpart = tpa + tpb;
  float wr2 = Wr2[hh];
  float ne = waveReduce(siluf(tpart)*wr2);
  if (lane == 0) e_node[node] += 0.25f*ne;   // per-node, single owner wave: no atomic
  float coeff = dsiluf(tpart)*wr2;
  // gP[lane] = sum_h c[h]*P1H[h][lane]; gs2[lane] = sum_h c[h]*Q2H[z][h][lane]  (coalesced)
  float gP, gs2;
  { float ga_=0.f,gb_=0.f,qa_=0.f,qb_=0.f;
    const float* Qz_ = Q2H + z*HIDR*KDIM + lane;
    const float* Ph_ = P1H + lane;
    #pragma unroll
    for (int h = 0; h < HIDR; h += 2){
      float c0_ = rlane(coeff, h), c1_ = rlane(coeff, h+1);
      ga_ += c0_*Ph_[ h   *KDIM];
      gb_ += c1_*Ph_[(h+1)*KDIM];
      qa_ += c0_*Qz_[ h   *KDIM];
      qb_ += c1_*Qz_[(h+1)*KDIM];
    }
    gP = ga_+gb_; gs2 = qa_+qb_;
  }
  // gF1' = Wmix0^T(dE/dfeats1 non-gather part) = pv0 + gs2
  gF1[node*KDIM+lane] = pv0[lane] + gs2;
  float u = t0 + 2.f*t1*a0 + 3.f*t2*a0*a0;
  float vl = gP*u;
  float gAr;
  MVLDS(vl, 1, gAr)
  gAr2[node*KDIM+lane].x = gAr * (1.0f/AVG_NEI_F);
}

#define NBWD_NODE (N_NODES/8)           // 1250
#define NBWD_EN   ((N_NODES+511)/512)   // 20 extra blocks: fused energy reduce

// ---------------- bwd: sender-gather gH + layer-0 node bwd (+fused energy) ----------------
__global__ __launch_bounds__(512) void k_bwd_gH0(
    const int* z_buf, const int* ptr_s, const int4* ps_pack,
    const float2* Ft2, const float2* gAr2c,
    const float* Cmu0R, const float* Wout0raw,
    const float* gF1,
    const float* A00, const float* theta0,
    const float* e_node, const int* batch, float* out_e,
    float2* gAr2){
  int tid = threadIdx.x;
  if (blockIdx.x >= NBWD_NODE){
    // fused k_energy: LDS pre-reduced segment sum
    __shared__ float part[G_SEG];
    if (tid < G_SEG) part[tid] = 0.f;
    __syncthreads();
    int n = (blockIdx.x - NBWD_NODE)*512 + tid;
    if (n < N_NODES) atomicAdd(&part[batch[n]], e_node[n]);
    __syncthreads();
    if (tid < G_SEG) atomicAdd(&out_e[tid], part[tid]);
    return;
  }
  __shared__ __align__(16) float smW[2][KDIM*LSTR];
  int w = tid >> 6, lane = tid & 63;
  STAGE2(Cmu0R, Wout0raw)
  int node = blockIdx.x*8 + w;
  float ga;
  GATHER_NODE(node, ptr_s, ps_pack, pk.y, LOADH_G2, ga)
  // gP = gF1'(node) + Cmu0.ga   (Cmu0 = Wmix0*Wup1, row-major staged)
  float gfm;
  MVLDS(ga, 0, gfm)
  float gP = gF1[node*KDIM+lane] + gfm;
  int z = z_buf[node];
  float a = A00[node*KDIM+lane];
  float t0 = theta0[(0*ZDIM+z)*KDIM+lane];
  float t1 = theta0[(1*ZDIM+z)*KDIM+lane];
  float t2 = theta0[(2*ZDIM+z)*KDIM+lane];
  float u = t0 + 2.f*t1*a + 3.f*t2*a*a;
  float vl = gP*u;
  float gAr;
  MVLDS(vl, 1, gAr)
  gAr2[node*KDIM+lane].y = gAr * (1.0f/AVG_NEI_F);
}

// per-edge gr/r -> evec[e].w  (4 edges/wave, 16 lanes x 4 k each, float4 loads)
__global__ __launch_bounds__(256) void k_gr(const int4* emeta, const float4* dF4,
                                            const float2* gAr2, const float* h1, const float* M0,
                                            float4* evec){
  int tid = threadIdx.x;
  int e = blockIdx.x*16 + (tid >> 4);
  int li = tid & 15;
  int4 m = emeta[e];              // {r, snd, rcv, ez}
  float r = __int_as_float(m.x);
  if (r >= RMAXF) return;
  float tp = r * (TBINS / RMAXF);
  int b = (int)tp; if (b > TBINS-1) b = TBINS-1;
  float fr = tp - (float)b;
  int k0 = li*4;
  const float4* dp = dF4 + b*KDIM + k0;
  float4 d0 = dp[0], d1 = dp[1], d2 = dp[2], d3 = dp[3];
  const float4* gp = (const float4*)(gAr2 + m.z*KDIM + k0);
  float4 g01 = gp[0], g23 = gp[1];          // {g0.x,g0.y,g1.x,g1.y},{g2.x,g2.y,g3.x,g3.y}
  float4 hv = *(const float4*)(h1 + m.y*KDIM + k0);
  float4 mv = *(const float4*)(M0 + m.w*KDIM + k0);
  float v;
  v  = g01.x*hv.x*(d0.z + fr*(d0.w-d0.z)) + g01.y*mv.x*(d0.x + fr*(d0.y-d0.x));
  v += g01.z*hv.y*(d1.z + fr*(d1.w-d1.z)) + g01.w*mv.y*(d1.x + fr*(d1.y-d1.x));
  v += g23.x*hv.z*(d2.z + fr*(d2.w-d2.z)) + g23.y*mv.z*(d2.x + fr*(d2.y-d2.x));
  v += g23.z*hv.w*(d3.z + fr*(d3.w-d3.z)) + g23.w*mv.w*(d3.x + fr*(d3.y-d3.x));
  #pragma unroll
  for (int off = 8; off > 0; off >>= 1) v += __shfl_xor(v, off);
  if (li == 0) evec[e].w = v / r;
}

// force gather: 16 lanes/node, both CSR lists, no atomics
__global__ __launch_bounds__(256) void k_force(const int* ptr_r, const int4* pr_pack,
                                               const int* ptr_s, const int4* ps_pack,
                                               const float4* evec,
                                               float* out_f){
  int tid = threadIdx.x;
  int node = blockIdx.x*16 + (tid >> 4);
  int li = tid & 15;
  float fx=0.f, fy=0.f, fz=0.f;
  int beg = ptr_r[node], end = ptr_r[node+1];
  for (int idx = beg + li; idx < end; idx += 16){
    int e = pr_pack[idx].w;
    float4 ev = evec[e];
    fx -= ev.w*ev.x; fy -= ev.w*ev.y; fz -= ev.w*ev.z;
  }
  beg = ptr_s[node]; end = ptr_s[node+1];
  for (int idx = beg + li; idx < end; idx += 16){
    int e = ps_pack[idx].z;
    float4 ev = evec[e];
    fx += ev.w*ev.x; fy += ev.w*ev.y; fz += ev.w*ev.z;
  }
  #pragma unroll
  for (int off = 8; off > 0; off >>= 1){
    fx += __shfl_xor(fx, off);
    fy += __shfl_xor(fy, off);
    fz += __shfl_xor(fz, off);
  }
  if (li == 0){
    out_f[node*3+0] = fx; out_f[node*3+1] = fy; out_f[node*3+2] = fz;
  }
}

extern "C" void kernel_launch(void* const* d_in, const int* in_sizes, int n_in,
                              void* d_out, int out_size, void* d_ws, size_t ws_size,
                              hipStream_t stream){
  const float* pos    = (const float*)d_in[0];
  const float* attrs  = (const float*)d_in[1];
  const float* shifts = (const float*)d_in[2];
  const float* aE     = (const float*)d_in[3];
  const float* We     = (const float*)d_in[4];
  const float* Wup    = (const float*)d_in[5];
  const float* R1     = (const float*)d_in[6];
  const float* R2     = (const float*)d_in[7];
  const float* R3     = (const float*)d_in[8];
  const float* R4     = (const float*)d_in[9];
  const float* Wout   = (const float*)d_in[10];
  const float* Wsc    = (const float*)d_in[11];
  const float* theta  = (const float*)d_in[12];
  const float* Wmix   = (const float*)d_in[13];
  const float* w_read0= (const float*)d_in[14];
  const float* Wr1    = (const float*)d_in[15];
  const float* Wr2    = (const float*)d_in[16];
  const int*   ei     = (const int*)d_in[17];
  const int*   batch  = (const int*)d_in[18];

  char* base = (char*)d_ws;
  size_t off = 0;
  auto alloc = [&](size_t bytes)->void*{
    void* p = base + off;
    off = (off + bytes + 255) & ~(size_t)255;
    return p;
  };
  float4* evec   = (float4*)alloc(N_EDGES*sizeof(float4));
  int4*   emeta  = (int4*)alloc(N_EDGES*sizeof(int4));
  int4*   pr_pack= (int4*)alloc(N_EDGES*sizeof(int4));
  int4*   ps_pack= (int4*)alloc(N_EDGES*sizeof(int4));
  float*  e_node = (float*)alloc(N_NODES*sizeof(float));
  float*  h1     = (float*)alloc(N_NODES*KDIM*sizeof(float));
  float*  sc1    = (float*)alloc(N_NODES*KDIM*sizeof(float));
  float*  A00    = (float*)alloc(N_NODES*KDIM*sizeof(float));
  float*  gF1    = (float*)alloc(N_NODES*KDIM*sizeof(float));
  float2* gAr2   = (float2*)alloc(N_NODES*KDIM*sizeof(float2));
  float2* Ft2_0  = (float2*)alloc((TBINS+2)*KDIM*sizeof(float2));
  float2* Ft2_1  = (float2*)alloc((TBINS+2)*KDIM*sizeof(float2));
  float4* dF4    = (float4*)alloc((TBINS+1)*KDIM*sizeof(float4));
  float*  M0     = (float*)alloc(ZDIM*KDIM*sizeof(float));
  float*  Msc0   = (float*)alloc(ZDIM*KDIM*sizeof(float));
  float*  WoT0   = (float*)alloc(KDIM*KDIM*sizeof(float));
  float*  WoT1   = (float*)alloc(KDIM*KDIM*sizeof(float));
  float*  Cmu0R  = (float*)alloc(KDIM*KDIM*sizeof(float));
  float*  Cmu0T  = (float*)alloc(KDIM*KDIM*sizeof(float));
  float*  WCz    = (float*)alloc(ZDIM*KDIM*KDIM*sizeof(float));
  float*  P1T    = (float*)alloc(KDIM*HIDR*sizeof(float));
  float*  P1H    = (float*)alloc(HIDR*KDIM*sizeof(float));
  float*  QtabT  = (float*)alloc(ZDIM*KDIM*HIDR*sizeof(float));
  float*  Q2H    = (float*)alloc(ZDIM*HIDR*KDIM*sizeof(float));
  float*  Wr1T   = (float*)alloc(HIDR*KDIM*sizeof(float));
  float*  biash  = (float*)alloc(ZDIM*KDIM*sizeof(float));
  float*  biass  = (float*)alloc(ZDIM*KDIM*sizeof(float));
  float*  pv0    = (float*)alloc(KDIM*sizeof(float));
  float*  c0z    = (float*)alloc(16*sizeof(float));
  int* z_buf = (int*)alloc(N_NODES*sizeof(int));
  int* cnt_r = (int*)alloc(N_NODES*sizeof(int));
  int* cnt_s = (int*)alloc(N_NODES*sizeof(int));
  int* ptr_r = (int*)alloc((N_NODES+1)*sizeof(int));
  int* ptr_s = (int*)alloc((N_NODES+1)*sizeof(int));
  int* cur_r = (int*)alloc(N_NODES*sizeof(int));
  int* cur_s = (int*)alloc(N_NODES*sizeof(int));

  float* out_e = (float*)d_out;
  float* out_f = out_e + G_SEG;

  hipMemsetAsync(d_out, 0, (size_t)out_size*sizeof(float), stream);

  const int NB8 = N_NODES/8;

  const float* Wout1 = Wout + 3*KDIM*KDIM;
  const float* theta1 = theta + 3*ZDIM*KDIM;

  k_setup<<<NSETUP,256,0,stream>>>(We, Wup, Wsc, Wout, Wmix, Wr1, w_read0, attrs, aE,
                                   R1, R2, R3, R4,
                                   M0, Msc0, WoT0, WoT1,
                                   Cmu0R, Cmu0T, WCz,
                                   P1T, P1H, QtabT, Wr1T, pv0,
                                   Ft2_0, Ft2_1, (float*)dF4,
                                   z_buf, e_node, cnt_r, cnt_s);
  k_edge_setup<<<EB_MAIN+EB_TAIL,256,0,stream>>>(pos, shifts, ei, z_buf,
                                   Wmix, Wup, Wsc, Msc0, QtabT, w_read0,
                                   Q2H, biash, biass, c0z,
                                   evec, emeta, cnt_r, cnt_s);
  k_scan<<<2,1024,0,stream>>>(cnt_r, ptr_r, cur_r, cnt_s, ptr_s, cur_s);
  k_fill<<<EB_MAIN,256,0,stream>>>(emeta, cur_r, cur_s, pr_pack, ps_pack);

  // ---- forward ----
  k_layer0_fwd<<<NB8,512,0,stream>>>(z_buf, ptr_r, pr_pack, Ft2_0, M0,
      WoT0, Cmu0T, WCz, theta, biash, biass, pv0, c0z,
      A00, h1, sc1, e_node);
  k_layer1_fwd_bwd<<<NB8,512,0,stream>>>(z_buf, ptr_r, pr_pack, Ft2_1, h1,
      WoT1, Wout1, theta1, sc1, P1T, Wr1, Wr2,
      P1H, Q2H, pv0,
      gAr2, gF1, e_node);

  // ---- backward (+fused energy blocks) ----
  k_bwd_gH0<<<NBWD_NODE + NBWD_EN,512,0,stream>>>(z_buf, ptr_s, ps_pack, Ft2_1, gAr2,
      Cmu0R, Wout, gF1, A00, theta,
      e_node, batch, out_e, gAr2);
  k_gr<<<N_EDGES/16,256,0,stream>>>(emeta, dF4, gAr2, h1, M0, evec);
  k_force<<<N_NODES/16,256,0,stream>>>(ptr_r, pr_pack, ptr_s, ps_pack, evec, out_f);
}